// Round 3
// baseline (38.091 us; speedup 1.0000x reference)
//
#include <hip/hip_runtime.h>
#include <math.h>

namespace {

constexpr int kBS      = 512;
constexpr int kNA      = 3;
constexpr int kGS      = 13;
constexpr int kAttrs   = 85;           // 5 + 80 classes
constexpr int kSpatial = kGS * kGS;    // 169
constexpr int kCells   = kBS * kNA * kSpatial;  // 259,584
constexpr float kStrideF = 32.0f;      // 416 / 13

constexpr int kBlockThreads  = 128;                   // 2 waves
constexpr int kChunkCells    = 32;                    // cells staged per chunk
constexpr int kNumChunks     = kBlockThreads / kChunkCells;   // 4
constexpr int kChunkFloats   = kChunkCells * kAttrs;  // 2,720 floats = 10,880 B
constexpr int kChunkFloat4   = kChunkFloats / 4;      // 680
constexpr int kBlockFloats   = kBlockThreads * kAttrs;

__device__ __forceinline__ float fsigmoid(float x) {
    return 1.0f / (1.0f + __expf(-x));
}

__global__ __launch_bounds__(kBlockThreads) void yolo_head_kernel(const float* __restrict__ x,
                                                                  float* __restrict__ out) {
    __shared__ float smem[2][kChunkFloats];   // double-buffered: 21,760 B

    const int tid  = threadIdx.x;
    const int cell = blockIdx.x * kBlockThreads + tid;   // grid sized exactly

    const int s  = cell % kSpatial;   // i*13 + j
    const int ba = cell / kSpatial;   // b*3 + a
    const int a  = ba % kNA;

    // x[b, a*85 + c, i, j] -> base + c*169; lanes have consecutive s -> coalesced.
    const float* __restrict__ xp = x + (size_t)ba * kAttrs * kSpatial + s;

    float v[kAttrs];
#pragma unroll
    for (int c = 0; c < kAttrs; ++c) {
        v[c] = xp[(size_t)c * kSpatial];
    }

    const float jf  = (float)(s % kGS);   // grid_x
    const float if_ = (float)(s / kGS);   // grid_y

    const float aw = (a == 0) ? 116.0f : (a == 1) ? 156.0f : 373.0f;
    const float ah = (a == 0) ?  90.0f : (a == 1) ? 198.0f : 326.0f;

    v[0] = (fsigmoid(v[0]) + jf) * kStrideF;     // bx
    v[1] = (fsigmoid(v[1]) + if_) * kStrideF;    // by
    v[2] = __expf(v[2]) * aw;                    // bw
    v[3] = __expf(v[3]) * ah;                    // bh
    v[4] = fsigmoid(v[4]);                       // conf

    // softmax over 80 class logits
    float m = v[5];
#pragma unroll
    for (int c = 6; c < kAttrs; ++c) m = fmaxf(m, v[c]);
    float sum = 0.0f;
#pragma unroll
    for (int c = 5; c < kAttrs; ++c) {
        const float e = __expf(v[c] - m);
        v[c] = e;
        sum += e;
    }
    const float inv = 1.0f / sum;
#pragma unroll
    for (int c = 5; c < kAttrs; ++c) v[c] *= inv;

    const int group = tid >> 5;   // which chunk this thread's cell belongs to
    const int lane  = tid & 31;

    // Stage chunk k: its 32 owner threads dump v[] to LDS buffer (k&1).
    // Lane stride 85 words (85 mod 32 = 21, odd) -> bank-conflict-free.
    auto stage = [&](int k) {
        if (group == k) {
            float* __restrict__ sp = &smem[k & 1][lane * kAttrs];
#pragma unroll
            for (int c = 0; c < kAttrs; ++c) sp[c] = v[c];
        }
    };

    stage(0);
    __syncthreads();

    for (int k = 0; k < kNumChunks; ++k) {
        if (k < kNumChunks - 1) stage(k + 1);   // fill other buffer while copying

        // Coalesced float4 copy of chunk k's contiguous output region.
        const float4* __restrict__ s4 = (const float4*)smem[k & 1];
        float4* __restrict__ out4 =
            (float4*)(out + (size_t)blockIdx.x * kBlockFloats + (size_t)k * kChunkFloats);
#pragma unroll
        for (int t = tid; t < kChunkFloat4; t += kBlockThreads) {
            out4[t] = s4[t];
        }
        __syncthreads();   // chunk copied; buffer (k&1) free for reuse, buffer (k+1&1) ready
    }
}

}  // namespace

extern "C" void kernel_launch(void* const* d_in, const int* in_sizes, int n_in,
                              void* d_out, int out_size, void* d_ws, size_t ws_size,
                              hipStream_t stream) {
    const float* x = (const float*)d_in[0];
    float* out = (float*)d_out;
    const int blocks = kCells / kBlockThreads;  // 2028 exactly
    yolo_head_kernel<<<blocks, kBlockThreads, 0, stream>>>(x, out);
}